// Round 14
// baseline (105.509 us; speedup 1.0000x reference)
//
#include <hip/hip_runtime.h>
#include <float.h>
#include <math.h>

#define NSAMPLE 8192
#define KSEL 9          // K+1: keep 9 smallest incl. self
#define KNN 8
#define BLK 512
#define EPS_F 1e-12f

#define ROWS_PB 8                    // rows per block -> 1024 blocks
#define RPT 8                        // rows per thread (all block rows)
#define LANES 64
#define NW 8                         // waves per block
#define KQT 16                       // scan iters per wave (1024 / 64)
#define BNDI 8                       // bound iters per wave (512 / 64), waves 0-3
#define BATCH 4
#define SLOTS 256                    // survivor slots per row (exp ~50)
#define SLOTP 257                    // padded stride (mod 32 == 1)
#define BP 257                       // bound minima stride (256 + 1 pad)
#define IDX_MASK 0x1FFFu             // low 13 bits = candidate index
#define VAL_MASK 0xFFFFE000u         // high 19 bits = d2 (sign+exp+10 mantissa)
#define PROW 73                      // merge-row stride (72 + 1 pad)
#define SROW 289                     // scratch stride (32*9 + 1)
#define SCALE (1.0f / (float)(NSAMPLE * KNN * 3))

__device__ __forceinline__ unsigned umn(unsigned a, unsigned b) { return a < b ? a : b; }
__device__ __forceinline__ unsigned umx(unsigned a, unsigned b) { return a > b ? a : b; }

// Branchless insert of x into descending-sorted s[0..8] (s[0]=worst, s[8]=best).
__device__ __forceinline__ void insert9(unsigned s[KSEL], unsigned x)
{
#pragma unroll
    for (int k = 0; k < KSEL - 1; ++k)
        s[k] = umx(s[k + 1], umn(x, s[k]));
    s[KSEL - 1] = umn(x, s[KSEL - 1]);
}

// Packed (d2 | idx). d2 clamped >= 0 so self packs minimal.
__device__ __forceinline__ unsigned pack_d2(float d2, int gidx)
{
    return (__float_as_uint(fmaxf(d2, 0.0f)) & VAL_MASK) | (unsigned)gidx;
}

// ---------------------------------------------------------------------------
// Kernel 1: one-time gather into compact L2-resident float4 arrays:
//   sm4 = (mean.xyz, |mean|^2), ss4 = (sh0.xyz, 0).
// ---------------------------------------------------------------------------
__global__ __launch_bounds__(256) void gather_k(
    const float* __restrict__ means, const float* __restrict__ sh0,
    const int* __restrict__ idx,
    float4* __restrict__ sm4, float4* __restrict__ ss4)
{
    int i = blockIdx.x * 256 + threadIdx.x;
    if (i >= NSAMPLE) return;
    int id = idx[i];
    const float* m = means + 3 * id;
    const float* s = sh0 + 3 * id;
    float mx = m[0], my = m[1], mz = m[2];
    sm4[i] = make_float4(mx, my, mz, fmaf(mx, mx, fmaf(my, my, mz * mz)));
    ss4[i] = make_float4(s[0], s[1], s[2], 0.0f);
}

// ---------------------------------------------------------------------------
// Kernel 2: 1024 blocks x 512 threads (8 waves, 32 waves/CU). Every thread
// owns ALL 8 block rows (R14: one coalesced 1 KB load feeds 512 evals; scan
// is 16 iters/wave). Wave w scans candidate octant [1024w, 1024w+1024).
// Survivors (~0.6%) compacted to per-row LDS lists under per-row __any
// branches; selection runs once at the end over ~50 entries/row.
// ---------------------------------------------------------------------------
__global__ __launch_bounds__(BLK, 8) void main_k(
    const float4* __restrict__ sm4, const float4* __restrict__ ss4,
    float* __restrict__ out)
{
    __shared__ unsigned surv[ROWS_PB * SLOTP];    // 8.2 KB survivor lists
    __shared__ unsigned scratch[ROWS_PB * SROW];  // 9.2 KB merge scratch
    __shared__ unsigned bpart[ROWS_PB * BP];      // 8.2 KB bound minima
    __shared__ unsigned partS[ROWS_PB * PROW];    // 2.3 KB merge scratch 2
    __shared__ unsigned scnt[ROWS_PB];
    __shared__ unsigned bnd[ROWS_PB];
    __shared__ float    red[ROWS_PB];

    const int t = threadIdx.x;
    const int lane = t & (LANES - 1);
    const int w = t >> 6;                       // 0..7 (wave id)
    if (t < ROWS_PB) scnt[t] = 0u;

    // Own-row coefficients for all 8 rows (bit-identical arithmetic to
    // candidate entries). All threads load the same 8 float4s -> L1-hot.
    float cX[RPT], cY[RPT], cZ[RPT], cW[RPT];
#pragma unroll
    for (int i = 0; i < RPT; ++i) {
        float4 p = sm4[blockIdx.x * ROWS_PB + i];
        cX[i] = -2.0f * p.x; cY[i] = -2.0f * p.y; cZ[i] = -2.0f * p.z;
        cW[i] = p.w;
    }

    // ---- Bound: waves 0-3 cover cands 0..2047; per lane an 8-cand slice.
    // Per row: 4 waves x 64 lanes = 256 disjoint-slice minima.
    if (w < 4) {
        unsigned pm[RPT];
#pragma unroll
        for (int i = 0; i < RPT; ++i) pm[i] = 0xFFFFFFFFu;
        const int b0 = w * (BNDI * LANES);
#pragma unroll
        for (int k = 0; k < BNDI; ++k) {
            const int ci = b0 + k * LANES + lane;
            float4 q = sm4[ci];                 // coalesced, L1/L2-hot
#pragma unroll
            for (int i = 0; i < RPT; ++i) {
                float d2 = fmaf(cX[i], q.x,
                           fmaf(cY[i], q.y, fmaf(cZ[i], q.z, cW[i] + q.w)));
                pm[i] = umn(pm[i], pack_d2(d2, ci));
            }
        }
#pragma unroll
        for (int i = 0; i < RPT; ++i)
            bpart[i * BP + w * LANES + lane] = pm[i];
    }
    __syncthreads();

    // Merge 256 minima/row -> bnd = 9th smallest (valid upper bound on the
    // row's true 9th: the 9 minima below it are 9 distinct candidates).
    if (t < 256) {                              // stage 1: 8 rows x 32 groups
        const int r1 = t & (ROWS_PB - 1);
        const int g = t >> 3;                   // 0..31
        unsigned s[KSEL];
#pragma unroll
        for (int k = 0; k < KSEL; ++k) s[k] = 0xFFFFFFFFu;
#pragma unroll
        for (int e = 0; e < 8; ++e)
            insert9(s, bpart[r1 * BP + g * 8 + e]);
#pragma unroll
        for (int k = 0; k < KSEL; ++k)
            scratch[r1 * SROW + g * KSEL + k] = s[k];
    }
    __syncthreads();
    if (t < 64) {                               // stage 2: 8 rows x 8 groups
        const int r1 = t & (ROWS_PB - 1);
        const int mg = t >> 3;                  // 0..7
        unsigned m[KSEL];
#pragma unroll
        for (int k = 0; k < KSEL; ++k) m[k] = 0xFFFFFFFFu;
#pragma unroll
        for (int e = 0; e < 4 * KSEL; ++e)
            insert9(m, scratch[r1 * SROW + (4 * mg) * KSEL + e]);
#pragma unroll
        for (int k = 0; k < KSEL; ++k)
            partS[r1 * PROW + mg * KSEL + k] = m[k];
    }
    __syncthreads();
    if (t < ROWS_PB) {                          // stage 3: 72 -> 9th
        unsigned m[KSEL];
#pragma unroll
        for (int k = 0; k < KSEL; ++k) m[k] = 0xFFFFFFFFu;
#pragma unroll
        for (int e = 0; e < 8 * KSEL; ++e)
            insert9(m, partS[t * PROW + e]);
        bnd[t] = m[0];
    }
    __syncthreads();

    // Float screen: pack(d2)|idx <= b implies bits(d2) <= (b|IDX_MASK);
    // positive floats -> uint order == float order. Superset; extras harmless.
    float bf[RPT];
#pragma unroll
    for (int i = 0; i < RPT; ++i)
        bf[i] = __uint_as_float(bnd[i] | IDX_MASK);

    // ---- Scan: barrier-free compaction over this wave's 1024 candidates --
    const int s0 = w * (KQT * LANES);
    for (int k0 = 0; k0 < KQT; k0 += BATCH) {
        float4 qr[BATCH];
#pragma unroll
        for (int u = 0; u < BATCH; ++u)
            qr[u] = sm4[s0 + (k0 + u) * LANES + lane];  // 4 loads in flight
#pragma unroll
        for (int u = 0; u < BATCH; ++u) {
            const int ci = s0 + (k0 + u) * LANES + lane;
#pragma unroll
            for (int i = 0; i < RPT; ++i) {
                float d2 = fmaf(cX[i], qr[u].x,
                           fmaf(cY[i], qr[u].y,
                           fmaf(cZ[i], qr[u].z, cW[i] + qr[u].w)));
                bool c = (d2 <= bf[i]);
                if (__any(c)) {                 // wave-uniform s_cbranch
                    if (c) {
                        unsigned pos = atomicAdd(&scnt[i], 1u);
                        if (pos < SLOTS)
                            surv[i * SLOTP + pos] = pack_d2(d2, ci);
                    }
                }
            }
        }
    }
    __syncthreads();                             // survivor lists complete

    // ---- Select: 32 threads/row over ~50 survivors, then 2-stage merge ---
    if (t < 256) {
        const int r1 = t & (ROWS_PB - 1);
        const int g = t >> 3;                   // 0..31
        const unsigned n = umn(scnt[r1], SLOTS);
        unsigned s[KSEL];
#pragma unroll
        for (int k = 0; k < KSEL; ++k) s[k] = 0xFFFFFFFFu;
        for (unsigned k = g; k < n; k += 32)
            insert9(s, surv[r1 * SLOTP + k]);
#pragma unroll
        for (int k = 0; k < KSEL; ++k)
            scratch[r1 * SROW + g * KSEL + k] = s[k];
    }
    __syncthreads();
    if (t < 64) {
        const int r1 = t & (ROWS_PB - 1);
        const int mg = t >> 3;                  // 0..7
        unsigned m[KSEL];
#pragma unroll
        for (int k = 0; k < KSEL; ++k) m[k] = 0xFFFFFFFFu;
#pragma unroll
        for (int e = 0; e < 4 * KSEL; ++e)
            insert9(m, scratch[r1 * SROW + (4 * mg) * KSEL + e]);
#pragma unroll
        for (int k = 0; k < KSEL; ++k)
            partS[r1 * PROW + mg * KSEL + k] = m[k];
    }
    __syncthreads();

    if (t < ROWS_PB) {                          // final merge + epilogue
        unsigned m[KSEL];
#pragma unroll
        for (int k = 0; k < KSEL; ++k) m[k] = 0xFFFFFFFFu;
#pragma unroll
        for (int e = 0; e < 8 * KSEL; ++e)
            insert9(m, partS[t * PROW + e]);

        // m[8] = global min (self, or identical-coordinate dup whose term is
        // 0 either way) -> dropped. m[0..7] = the 8 neighbors.
        const int gr = blockIdx.x * ROWS_PB + t;
        float4 pm4 = sm4[gr];
        float4 ps4 = ss4[gr];
        float acc = 0.0f;
#pragma unroll
        for (int k = 0; k < KNN; ++k) {
            int j = (int)(m[k] & IDX_MASK);
            float4 qm = sm4[j];
            float dx = pm4.x - qm.x, dy = pm4.y - qm.y, dz = pm4.z - qm.z;
            float d2 = fmaf(dx, dx, fmaf(dy, dy, dz * dz));
            float d = sqrtf(fmaxf(d2, EPS_F));
            float wgt = expf(-d);
            float4 qs = ss4[j];
            float ax = ps4.x - qs.x, ay = ps4.y - qs.y, az = ps4.z - qs.z;
            acc += wgt * (ax * ax + ay * ay + az * az);
        }
        red[t] = acc;
    }
    __syncthreads();
    if (t == 0) {
        float ssum = 0.0f;
#pragma unroll
        for (int i = 0; i < ROWS_PB; ++i) ssum += red[i];
        atomicAdd(out, ssum * SCALE);
    }
}

// ---------------------------------------------------------------------------
extern "C" void kernel_launch(void* const* d_in, const int* in_sizes, int n_in,
                              void* d_out, int out_size, void* d_ws, size_t ws_size,
                              hipStream_t stream)
{
    const float* means = (const float*)d_in[0];
    const float* sh0   = (const float*)d_in[1];
    const int*   idxp  = (const int*)d_in[2];

    float4* sm4 = (float4*)d_ws;                 // 128 KB
    float4* ss4 = sm4 + NSAMPLE;                 // 128 KB

    gather_k<<<NSAMPLE / 256, 256, 0, stream>>>(means, sh0, idxp, sm4, ss4);
    main_k<<<NSAMPLE / ROWS_PB, BLK, 0, stream>>>(sm4, ss4, (float*)d_out);
}

// Round 15
// 105.186 us; speedup vs baseline: 1.0031x; 1.0031x over previous
//
#include <hip/hip_runtime.h>
#include <float.h>
#include <math.h>

#define NSAMPLE 8192
#define KSEL 9          // K+1: keep 9 smallest incl. self
#define KNN 8
#define BLK 512
#define EPS_F 1e-12f

#define ROWS_PB 8                    // rows per block -> 1024 blocks
#define NBLOCKS (NSAMPLE / ROWS_PB)  // 1024
#define RPT 8                        // rows per thread (all block rows)
#define LANES 64
#define KQT 16                       // scan iters per wave (1024 / 64)
#define BNDI 8                       // bound iters per wave (512 / 64), waves 0-3
#define BATCH 4
#define SLOTS 256                    // survivor slots per row (exp ~50)
#define SLOTP 257                    // padded stride (mod 32 == 1)
#define BP 257                       // bound minima stride (256 + 1 pad)
#define IDX_MASK 0x1FFFu             // low 13 bits = candidate index
#define VAL_MASK 0xFFFFE000u         // high 19 bits = d2 (sign+exp+10 mantissa)
#define PROW 73                      // merge-row stride (72 + 1 pad)
#define SROW 289                     // scratch stride (32*9 + 1)
#define SCALE (1.0f / (float)(NSAMPLE * KNN * 3))

__device__ __forceinline__ unsigned umn(unsigned a, unsigned b) { return a < b ? a : b; }
__device__ __forceinline__ unsigned umx(unsigned a, unsigned b) { return a > b ? a : b; }

// Branchless insert of x into descending-sorted s[0..8] (s[0]=worst, s[8]=best).
__device__ __forceinline__ void insert9(unsigned s[KSEL], unsigned x)
{
#pragma unroll
    for (int k = 0; k < KSEL - 1; ++k)
        s[k] = umx(s[k + 1], umn(x, s[k]));
    s[KSEL - 1] = umn(x, s[KSEL - 1]);
}

// Packed (d2 | idx). d2 clamped >= 0 so self packs minimal.
__device__ __forceinline__ unsigned pack_d2(float d2, int gidx)
{
    return (__float_as_uint(fmaxf(d2, 0.0f)) & VAL_MASK) | (unsigned)gidx;
}

// ---------------------------------------------------------------------------
// Kernel 1: one-time gather into compact L2-resident float4 arrays:
//   sm4 = (mean.xyz, |mean|^2), ss4 = (sh0.xyz, 0).
// ---------------------------------------------------------------------------
__global__ __launch_bounds__(256) void gather_k(
    const float* __restrict__ means, const float* __restrict__ sh0,
    const int* __restrict__ idx,
    float4* __restrict__ sm4, float4* __restrict__ ss4)
{
    int i = blockIdx.x * 256 + threadIdx.x;
    if (i >= NSAMPLE) return;
    int id = idx[i];
    const float* m = means + 3 * id;
    const float* s = sh0 + 3 * id;
    float mx = m[0], my = m[1], mz = m[2];
    sm4[i] = make_float4(mx, my, mz, fmaf(mx, mx, fmaf(my, my, mz * mz)));
    ss4[i] = make_float4(s[0], s[1], s[2], 0.0f);
}

// ---------------------------------------------------------------------------
// Kernel 2: identical to R14 EXCEPT the tail: per-block result is a plain
// coalesced store to partial[blockIdx.x] instead of atomicAdd to one global
// address. R15 theory: 1024 same-address device-scope fp32 RMWs serialize at
// the L2 bank and are the invariant ~40 us floor of R11-R14.
// ---------------------------------------------------------------------------
__global__ __launch_bounds__(BLK, 8) void main_k(
    const float4* __restrict__ sm4, const float4* __restrict__ ss4,
    float* __restrict__ partial)
{
    __shared__ unsigned surv[ROWS_PB * SLOTP];    // 8.2 KB survivor lists
    __shared__ unsigned scratch[ROWS_PB * SROW];  // 9.2 KB merge scratch
    __shared__ unsigned bpart[ROWS_PB * BP];      // 8.2 KB bound minima
    __shared__ unsigned partS[ROWS_PB * PROW];    // 2.3 KB merge scratch 2
    __shared__ unsigned scnt[ROWS_PB];
    __shared__ unsigned bnd[ROWS_PB];
    __shared__ float    red[ROWS_PB];

    const int t = threadIdx.x;
    const int lane = t & (LANES - 1);
    const int w = t >> 6;                       // 0..7 (wave id)
    if (t < ROWS_PB) scnt[t] = 0u;

    // Own-row coefficients for all 8 rows (bit-identical arithmetic to
    // candidate entries). All threads load the same 8 float4s -> L1-hot.
    float cX[RPT], cY[RPT], cZ[RPT], cW[RPT];
#pragma unroll
    for (int i = 0; i < RPT; ++i) {
        float4 p = sm4[blockIdx.x * ROWS_PB + i];
        cX[i] = -2.0f * p.x; cY[i] = -2.0f * p.y; cZ[i] = -2.0f * p.z;
        cW[i] = p.w;
    }

    // ---- Bound: waves 0-3 cover cands 0..2047; per lane an 8-cand slice.
    // Per row: 4 waves x 64 lanes = 256 disjoint-slice minima.
    if (w < 4) {
        unsigned pm[RPT];
#pragma unroll
        for (int i = 0; i < RPT; ++i) pm[i] = 0xFFFFFFFFu;
        const int b0 = w * (BNDI * LANES);
#pragma unroll
        for (int k = 0; k < BNDI; ++k) {
            const int ci = b0 + k * LANES + lane;
            float4 q = sm4[ci];                 // coalesced, L1/L2-hot
#pragma unroll
            for (int i = 0; i < RPT; ++i) {
                float d2 = fmaf(cX[i], q.x,
                           fmaf(cY[i], q.y, fmaf(cZ[i], q.z, cW[i] + q.w)));
                pm[i] = umn(pm[i], pack_d2(d2, ci));
            }
        }
#pragma unroll
        for (int i = 0; i < RPT; ++i)
            bpart[i * BP + w * LANES + lane] = pm[i];
    }
    __syncthreads();

    // Merge 256 minima/row -> bnd = 9th smallest (valid upper bound on the
    // row's true 9th: the 9 minima below it are 9 distinct candidates).
    if (t < 256) {                              // stage 1: 8 rows x 32 groups
        const int r1 = t & (ROWS_PB - 1);
        const int g = t >> 3;                   // 0..31
        unsigned s[KSEL];
#pragma unroll
        for (int k = 0; k < KSEL; ++k) s[k] = 0xFFFFFFFFu;
#pragma unroll
        for (int e = 0; e < 8; ++e)
            insert9(s, bpart[r1 * BP + g * 8 + e]);
#pragma unroll
        for (int k = 0; k < KSEL; ++k)
            scratch[r1 * SROW + g * KSEL + k] = s[k];
    }
    __syncthreads();
    if (t < 64) {                               // stage 2: 8 rows x 8 groups
        const int r1 = t & (ROWS_PB - 1);
        const int mg = t >> 3;                  // 0..7
        unsigned m[KSEL];
#pragma unroll
        for (int k = 0; k < KSEL; ++k) m[k] = 0xFFFFFFFFu;
#pragma unroll
        for (int e = 0; e < 4 * KSEL; ++e)
            insert9(m, scratch[r1 * SROW + (4 * mg) * KSEL + e]);
#pragma unroll
        for (int k = 0; k < KSEL; ++k)
            partS[r1 * PROW + mg * KSEL + k] = m[k];
    }
    __syncthreads();
    if (t < ROWS_PB) {                          // stage 3: 72 -> 9th
        unsigned m[KSEL];
#pragma unroll
        for (int k = 0; k < KSEL; ++k) m[k] = 0xFFFFFFFFu;
#pragma unroll
        for (int e = 0; e < 8 * KSEL; ++e)
            insert9(m, partS[t * PROW + e]);
        bnd[t] = m[0];
    }
    __syncthreads();

    // Float screen: pack(d2)|idx <= b implies bits(d2) <= (b|IDX_MASK);
    // positive floats -> uint order == float order. Superset; extras harmless.
    float bf[RPT];
#pragma unroll
    for (int i = 0; i < RPT; ++i)
        bf[i] = __uint_as_float(bnd[i] | IDX_MASK);

    // ---- Scan: barrier-free compaction over this wave's 1024 candidates --
    const int s0 = w * (KQT * LANES);
    for (int k0 = 0; k0 < KQT; k0 += BATCH) {
        float4 qr[BATCH];
#pragma unroll
        for (int u = 0; u < BATCH; ++u)
            qr[u] = sm4[s0 + (k0 + u) * LANES + lane];  // 4 loads in flight
#pragma unroll
        for (int u = 0; u < BATCH; ++u) {
            const int ci = s0 + (k0 + u) * LANES + lane;
#pragma unroll
            for (int i = 0; i < RPT; ++i) {
                float d2 = fmaf(cX[i], qr[u].x,
                           fmaf(cY[i], qr[u].y,
                           fmaf(cZ[i], qr[u].z, cW[i] + qr[u].w)));
                bool c = (d2 <= bf[i]);
                if (__any(c)) {                 // wave-uniform s_cbranch
                    if (c) {
                        unsigned pos = atomicAdd(&scnt[i], 1u);
                        if (pos < SLOTS)
                            surv[i * SLOTP + pos] = pack_d2(d2, ci);
                    }
                }
            }
        }
    }
    __syncthreads();                             // survivor lists complete

    // ---- Select: 32 threads/row over ~50 survivors, then 2-stage merge ---
    if (t < 256) {
        const int r1 = t & (ROWS_PB - 1);
        const int g = t >> 3;                   // 0..31
        const unsigned n = umn(scnt[r1], SLOTS);
        unsigned s[KSEL];
#pragma unroll
        for (int k = 0; k < KSEL; ++k) s[k] = 0xFFFFFFFFu;
        for (unsigned k = g; k < n; k += 32)
            insert9(s, surv[r1 * SLOTP + k]);
#pragma unroll
        for (int k = 0; k < KSEL; ++k)
            scratch[r1 * SROW + g * KSEL + k] = s[k];
    }
    __syncthreads();
    if (t < 64) {
        const int r1 = t & (ROWS_PB - 1);
        const int mg = t >> 3;                  // 0..7
        unsigned m[KSEL];
#pragma unroll
        for (int k = 0; k < KSEL; ++k) m[k] = 0xFFFFFFFFu;
#pragma unroll
        for (int e = 0; e < 4 * KSEL; ++e)
            insert9(m, scratch[r1 * SROW + (4 * mg) * KSEL + e]);
#pragma unroll
        for (int k = 0; k < KSEL; ++k)
            partS[r1 * PROW + mg * KSEL + k] = m[k];
    }
    __syncthreads();

    if (t < ROWS_PB) {                          // final merge + epilogue
        unsigned m[KSEL];
#pragma unroll
        for (int k = 0; k < KSEL; ++k) m[k] = 0xFFFFFFFFu;
#pragma unroll
        for (int e = 0; e < 8 * KSEL; ++e)
            insert9(m, partS[t * PROW + e]);

        // m[8] = global min (self, or identical-coordinate dup whose term is
        // 0 either way) -> dropped. m[0..7] = the 8 neighbors.
        const int gr = blockIdx.x * ROWS_PB + t;
        float4 pm4 = sm4[gr];
        float4 ps4 = ss4[gr];
        float acc = 0.0f;
#pragma unroll
        for (int k = 0; k < KNN; ++k) {
            int j = (int)(m[k] & IDX_MASK);
            float4 qm = sm4[j];
            float dx = pm4.x - qm.x, dy = pm4.y - qm.y, dz = pm4.z - qm.z;
            float d2 = fmaf(dx, dx, fmaf(dy, dy, dz * dz));
            float d = sqrtf(fmaxf(d2, EPS_F));
            float wgt = expf(-d);
            float4 qs = ss4[j];
            float ax = ps4.x - qs.x, ay = ps4.y - qs.y, az = ps4.z - qs.z;
            acc += wgt * (ax * ax + ay * ay + az * az);
        }
        red[t] = acc;
    }
    __syncthreads();
    if (t == 0) {
        float ssum = 0.0f;
#pragma unroll
        for (int i = 0; i < ROWS_PB; ++i) ssum += red[i];
        partial[blockIdx.x] = ssum;              // plain store, NO atomic
    }
}

// ---------------------------------------------------------------------------
// Kernel 3: reduce 1024 block partials -> scalar. One block; removes the
// 1024-way same-address atomic contention from main_k's critical path.
// ---------------------------------------------------------------------------
__global__ __launch_bounds__(256) void reduce_k(
    const float* __restrict__ partial, float* __restrict__ out)
{
    __shared__ float sbuf[4];
    int t = threadIdx.x;
    float v = 0.0f;
    for (int i = t; i < NBLOCKS; i += 256) v += partial[i];
    for (int off = 32; off > 0; off >>= 1) v += __shfl_down(v, off);
    if ((t & 63) == 0) sbuf[t >> 6] = v;
    __syncthreads();
    if (t == 0) {
        float s = sbuf[0] + sbuf[1] + sbuf[2] + sbuf[3];
        out[0] = s * SCALE;
    }
}

// ---------------------------------------------------------------------------
extern "C" void kernel_launch(void* const* d_in, const int* in_sizes, int n_in,
                              void* d_out, int out_size, void* d_ws, size_t ws_size,
                              hipStream_t stream)
{
    const float* means = (const float*)d_in[0];
    const float* sh0   = (const float*)d_in[1];
    const int*   idxp  = (const int*)d_in[2];

    float4* sm4 = (float4*)d_ws;                 // 128 KB
    float4* ss4 = sm4 + NSAMPLE;                 // 128 KB
    float*  partial = (float*)(ss4 + NSAMPLE);   // 4 KB

    gather_k<<<NSAMPLE / 256, 256, 0, stream>>>(means, sh0, idxp, sm4, ss4);
    main_k<<<NBLOCKS, BLK, 0, stream>>>(sm4, ss4, partial);
    reduce_k<<<1, 256, 0, stream>>>(partial, (float*)d_out);
}

// Round 16
// 101.493 us; speedup vs baseline: 1.0396x; 1.0364x over previous
//
#include <hip/hip_runtime.h>
#include <float.h>
#include <math.h>

#define NSAMPLE 8192
#define KSEL 9          // K+1: keep 9 smallest incl. self
#define KNN 8
#define BLK 512
#define EPS_F 1e-12f

#define ROWS_PB 8                    // rows per block -> 1024 blocks
#define NBLOCKS (NSAMPLE / ROWS_PB)  // 1024
#define RPT 4                        // rows per thread (rpar, +2, +4, +6)
#define LANES 64
#define KQT 32                       // scan iters per wave (2048 / 64)
#define BNDI 8                       // bound iters per wave (512 / 64)
#define BATCH 4
#define WCAP 32                      // survivor cap per (wave,row-slot) list
#define BP 257                       // bound minima stride (256 + 1 pad)
#define IDX_MASK 0x1FFFu             // low 13 bits = candidate index
#define VAL_MASK 0xFFFFE000u         // high 19 bits = d2 (sign+exp+10 mantissa)
#define PROW 73                      // merge-row stride (72 + 1 pad)
#define SROW 289                     // scratch stride (32*9 + 1)
#define SCALE (1.0f / (float)(NSAMPLE * KNN * 3))

__device__ __forceinline__ unsigned umn(unsigned a, unsigned b) { return a < b ? a : b; }
__device__ __forceinline__ unsigned umx(unsigned a, unsigned b) { return a > b ? a : b; }

// Branchless insert of x into descending-sorted s[0..8] (s[0]=worst, s[8]=best).
__device__ __forceinline__ void insert9(unsigned s[KSEL], unsigned x)
{
#pragma unroll
    for (int k = 0; k < KSEL - 1; ++k)
        s[k] = umx(s[k + 1], umn(x, s[k]));
    s[KSEL - 1] = umn(x, s[KSEL - 1]);
}

// Packed (d2 | idx). d2 clamped >= 0 so self packs minimal.
__device__ __forceinline__ unsigned pack_d2(float d2, int gidx)
{
    return (__float_as_uint(fmaxf(d2, 0.0f)) & VAL_MASK) | (unsigned)gidx;
}

// ---------------------------------------------------------------------------
// Kernel 1: one-time gather into compact L2-resident float4 arrays:
//   sm4 = (mean.xyz, |mean|^2), ss4 = (sh0.xyz, 0).
// ---------------------------------------------------------------------------
__global__ __launch_bounds__(256) void gather_k(
    const float* __restrict__ means, const float* __restrict__ sh0,
    const int* __restrict__ idx,
    float4* __restrict__ sm4, float4* __restrict__ ss4)
{
    int i = blockIdx.x * 256 + threadIdx.x;
    if (i >= NSAMPLE) return;
    int id = idx[i];
    const float* m = means + 3 * id;
    const float* s = sh0 + 3 * id;
    float mx = m[0], my = m[1], mz = m[2];
    sm4[i] = make_float4(mx, my, mz, fmaf(mx, mx, fmaf(my, my, mz * mz)));
    ss4[i] = make_float4(s[0], s[1], s[2], 0.0f);
}

// ---------------------------------------------------------------------------
// Kernel 2: R13 shape (1024 blocks x 512 thr, RPT=4: wave (rpar=w&1,
// quarter=w>>1) scans cands [q*2048,(q+1)*2048) for rows rpar+2i), but the
// compaction is ZERO-ATOMIC: one merged screen + __any branch per candidate
// (~32% taken); inside, per-row __ballot + popcount-prefix writes into a
// PRIVATE (wave,row-slot) LDS list; list base advances by wave-uniform scalar
// popcount. R16 theory: R11-R15's invariant ~40us floor = LDS-atomic
// serialization + 8 ballots/branches per candidate-group.
// ---------------------------------------------------------------------------
__global__ __launch_bounds__(BLK, 8) void main_k(
    const float4* __restrict__ sm4, const float4* __restrict__ ss4,
    float* __restrict__ partial)
{
    __shared__ unsigned wl[8 * RPT * WCAP];       // 4 KB private survivor lists
    __shared__ unsigned wcnt[8 * RPT];
    __shared__ unsigned scratch[ROWS_PB * SROW];  // 9.2 KB bound-merge scratch
    __shared__ unsigned bpart[ROWS_PB * BP];      // 8.2 KB bound minima
    __shared__ unsigned partS[ROWS_PB * PROW];    // 2.3 KB merge scratch 2
    __shared__ unsigned bnd[ROWS_PB];
    __shared__ float    red[ROWS_PB];

    const int t = threadIdx.x;
    const int lane = t & (LANES - 1);
    const int w = t >> 6;                       // 0..7 (wave id)
    const int rpar = w & 1;
    const int quarter = w >> 1;                 // 0..3
    const unsigned long long lmask_lt = (1ull << lane) - 1ull;

    // Own-row coefficients (bit-identical arithmetic to candidate entries).
    float cX[RPT], cY[RPT], cZ[RPT], cW[RPT];
#pragma unroll
    for (int i = 0; i < RPT; ++i) {
        float4 p = sm4[blockIdx.x * ROWS_PB + rpar + 2 * i];
        cX[i] = -2.0f * p.x; cY[i] = -2.0f * p.y; cZ[i] = -2.0f * p.z;
        cW[i] = p.w;
    }

    // ---- Bound: per-lane packed min over an 8-cand slice of cands 0..2047.
    // Per row: 4 quarters x 64 lanes = 256 disjoint-slice minima.
    {
        unsigned pm[RPT];
#pragma unroll
        for (int i = 0; i < RPT; ++i) pm[i] = 0xFFFFFFFFu;
        const int b0 = quarter * (BNDI * LANES);
#pragma unroll
        for (int k = 0; k < BNDI; ++k) {
            const int ci = b0 + k * LANES + lane;
            float4 q = sm4[ci];                 // coalesced, L1/L2-hot
#pragma unroll
            for (int i = 0; i < RPT; ++i) {
                float d2 = fmaf(cX[i], q.x,
                           fmaf(cY[i], q.y, fmaf(cZ[i], q.z, cW[i] + q.w)));
                pm[i] = umn(pm[i], pack_d2(d2, ci));
            }
        }
#pragma unroll
        for (int i = 0; i < RPT; ++i)
            bpart[(rpar + 2 * i) * BP + quarter * LANES + lane] = pm[i];
    }
    __syncthreads();

    // Merge 256 minima/row -> bnd = 9th smallest (valid upper bound on the
    // row's true 9th: the 9 minima below it are 9 distinct candidates).
    if (t < 256) {                              // stage 1: 8 rows x 32 groups
        const int r1 = t & (ROWS_PB - 1);
        const int g = t >> 3;                   // 0..31
        unsigned s[KSEL];
#pragma unroll
        for (int k = 0; k < KSEL; ++k) s[k] = 0xFFFFFFFFu;
#pragma unroll
        for (int e = 0; e < 8; ++e)
            insert9(s, bpart[r1 * BP + g * 8 + e]);
#pragma unroll
        for (int k = 0; k < KSEL; ++k)
            scratch[r1 * SROW + g * KSEL + k] = s[k];
    }
    __syncthreads();
    if (t < 64) {                               // stage 2: 8 rows x 8 groups
        const int r1 = t & (ROWS_PB - 1);
        const int mg = t >> 3;                  // 0..7
        unsigned m[KSEL];
#pragma unroll
        for (int k = 0; k < KSEL; ++k) m[k] = 0xFFFFFFFFu;
#pragma unroll
        for (int e = 0; e < 4 * KSEL; ++e)
            insert9(m, scratch[r1 * SROW + (4 * mg) * KSEL + e]);
#pragma unroll
        for (int k = 0; k < KSEL; ++k)
            partS[r1 * PROW + mg * KSEL + k] = m[k];
    }
    __syncthreads();
    if (t < ROWS_PB) {                          // stage 3: 72 -> 9th
        unsigned m[KSEL];
#pragma unroll
        for (int k = 0; k < KSEL; ++k) m[k] = 0xFFFFFFFFu;
#pragma unroll
        for (int e = 0; e < 8 * KSEL; ++e)
            insert9(m, partS[t * PROW + e]);
        bnd[t] = m[0];
    }
    __syncthreads();

    // Float screen: pack(d2)|idx <= b implies bits(d2) <= (b|IDX_MASK);
    // positive floats -> uint order == float order. Superset; extras harmless.
    float bf[RPT];
#pragma unroll
    for (int i = 0; i < RPT; ++i)
        bf[i] = __uint_as_float(bnd[rpar + 2 * i] | IDX_MASK);

    // ---- Scan: merged screen, one branch per candidate, zero atomics -----
    unsigned base[RPT];
#pragma unroll
    for (int i = 0; i < RPT; ++i) base[i] = 0u;

    const int s0 = quarter * (KQT * LANES);
    for (int k0 = 0; k0 < KQT; k0 += BATCH) {
        float4 qr[BATCH];
#pragma unroll
        for (int u = 0; u < BATCH; ++u)
            qr[u] = sm4[s0 + (k0 + u) * LANES + lane];  // 4 loads in flight
#pragma unroll
        for (int u = 0; u < BATCH; ++u) {
            const int ci = s0 + (k0 + u) * LANES + lane;
            float d2[RPT];
#pragma unroll
            for (int i = 0; i < RPT; ++i)
                d2[i] = fmaf(cX[i], qr[u].x,
                        fmaf(cY[i], qr[u].y,
                        fmaf(cZ[i], qr[u].z, cW[i] + qr[u].w)));
            float mrg = d2[0] - bf[0];
#pragma unroll
            for (int i = 1; i < RPT; ++i)
                mrg = fminf(mrg, d2[i] - bf[i]);
            if (__any(mrg <= 0.0f)) {            // single branch, ~32% taken
#pragma unroll
                for (int i = 0; i < RPT; ++i) {
                    bool c = (d2[i] <= bf[i]);
                    unsigned long long mk = __ballot(c);
                    if (mk) {                    // scalar-uniform test
                        unsigned pos = base[i] +
                            (unsigned)__popcll(mk & lmask_lt);
                        if (c && pos < WCAP)
                            wl[(w * RPT + i) * WCAP + pos] = pack_d2(d2[i], ci);
                        base[i] += (unsigned)__popcll(mk);  // uniform scalar
                    }
                }
            }
        }
    }
    if (lane == 0) {
#pragma unroll
        for (int i = 0; i < RPT; ++i)
            wcnt[w * RPT + i] = umn(base[i], WCAP);
    }
    __syncthreads();                             // survivor lists complete

    // ---- Select: 32 tasks, each merges one (wave,row-slot) list ----------
    if (t < 32) {
        const int r1 = t & (ROWS_PB - 1);        // row
        const int q = t >> 3;                    // 0..3 quarter
        const int wv = 2 * q + (r1 & 1);         // wave holding this row's list
        const int li = wv * RPT + (r1 >> 1);
        const unsigned n = wcnt[li];
        unsigned s[KSEL];
#pragma unroll
        for (int k = 0; k < KSEL; ++k) s[k] = 0xFFFFFFFFu;
        for (unsigned k = 0; k < n; ++k)
            insert9(s, wl[li * WCAP + k]);
#pragma unroll
        for (int k = 0; k < KSEL; ++k)
            partS[r1 * PROW + q * KSEL + k] = s[k];
    }
    __syncthreads();

    if (t < ROWS_PB) {                          // final 36-merge + epilogue
        unsigned m[KSEL];
#pragma unroll
        for (int k = 0; k < KSEL; ++k) m[k] = 0xFFFFFFFFu;
#pragma unroll
        for (int e = 0; e < 4 * KSEL; ++e)
            insert9(m, partS[t * PROW + e]);

        // m[8] = global min (self, or identical-coordinate dup whose term is
        // 0 either way) -> dropped. m[0..7] = the 8 neighbors.
        const int gr = blockIdx.x * ROWS_PB + t;
        float4 pm4 = sm4[gr];
        float4 ps4 = ss4[gr];
        float acc = 0.0f;
#pragma unroll
        for (int k = 0; k < KNN; ++k) {
            int j = (int)(m[k] & IDX_MASK);
            float4 qm = sm4[j];
            float dx = pm4.x - qm.x, dy = pm4.y - qm.y, dz = pm4.z - qm.z;
            float d2 = fmaf(dx, dx, fmaf(dy, dy, dz * dz));
            float d = sqrtf(fmaxf(d2, EPS_F));
            float wgt = expf(-d);
            float4 qs = ss4[j];
            float ax = ps4.x - qs.x, ay = ps4.y - qs.y, az = ps4.z - qs.z;
            acc += wgt * (ax * ax + ay * ay + az * az);
        }
        red[t] = acc;
    }
    __syncthreads();
    if (t == 0) {
        float ssum = 0.0f;
#pragma unroll
        for (int i = 0; i < ROWS_PB; ++i) ssum += red[i];
        partial[blockIdx.x] = ssum;              // plain store
    }
}

// ---------------------------------------------------------------------------
// Kernel 3: reduce 1024 block partials -> scalar (cost ~0, proven R15).
// ---------------------------------------------------------------------------
__global__ __launch_bounds__(256) void reduce_k(
    const float* __restrict__ partial, float* __restrict__ out)
{
    __shared__ float sbuf[4];
    int t = threadIdx.x;
    float v = 0.0f;
    for (int i = t; i < NBLOCKS; i += 256) v += partial[i];
    for (int off = 32; off > 0; off >>= 1) v += __shfl_down(v, off);
    if ((t & 63) == 0) sbuf[t >> 6] = v;
    __syncthreads();
    if (t == 0) {
        float s = sbuf[0] + sbuf[1] + sbuf[2] + sbuf[3];
        out[0] = s * SCALE;
    }
}

// ---------------------------------------------------------------------------
extern "C" void kernel_launch(void* const* d_in, const int* in_sizes, int n_in,
                              void* d_out, int out_size, void* d_ws, size_t ws_size,
                              hipStream_t stream)
{
    const float* means = (const float*)d_in[0];
    const float* sh0   = (const float*)d_in[1];
    const int*   idxp  = (const int*)d_in[2];

    float4* sm4 = (float4*)d_ws;                 // 128 KB
    float4* ss4 = sm4 + NSAMPLE;                 // 128 KB
    float*  partial = (float*)(ss4 + NSAMPLE);   // 4 KB

    gather_k<<<NSAMPLE / 256, 256, 0, stream>>>(means, sh0, idxp, sm4, ss4);
    main_k<<<NBLOCKS, BLK, 0, stream>>>(sm4, ss4, partial);
    reduce_k<<<1, 256, 0, stream>>>(partial, (float*)d_out);
}